// Round 7
// baseline (4183.149 us; speedup 1.0000x reference)
//
#include <hip/hip_runtime.h>
#include <hip/hip_bf16.h>

// ---------------------------------------------------------------------------
// BiLSTM T=512 B=64 D=H=512, both scans run forward (reference bug preserved).
// R7: h flows through `out` itself (time-extended, no address reuse within a
// launch): writer publishes h f32 via write-through agent atomic b64 stores;
// readers use PLAIN CACHED dwordx4 loads (cold-miss fetches fresh L3 data;
// inter-dispatch CP flush/invalidate kills cross-launch staleness) +
// v_cvt_pk_bf16_f32 to build MFMA A-frags. hbuf deleted. t=0 skips h-GEMM
// (h(-1)=0). Distributed per-direction flags with s_sleep poll (R6-proven),
// W fully LDS-resident, x-part GEMM of t+1 overlapped past the signal.
// ---------------------------------------------------------------------------

typedef short s8v __attribute__((ext_vector_type(8)));   // 8 x bf16 bits
typedef float f4v __attribute__((ext_vector_type(4)));

#define T_STEPS 512
#define BATCH   64
#define KDIM    1024          // D + H
#define NB_DIR  64            // blocks per direction
#define HS      8             // hidden units per block
#define COLS    32            // 4 gates * HS
#define NBLK    (2*NB_DIR)
#define WP      1032          // W LDS pitch (ushort): 1024 + 8 pad

// workspace byte offsets
#define WS_XB   0u                      // x bf16: 512*64*512*2      = 33554432
#define WS_WT   33554432u               // Wt bf16: 2*64*32*1024*2   =  8388608
#define WS_BIAS 41943040u               // bias f32: 2*2048*4        =    16384
#define WS_FLG  41959424u               // 128 flag dwords (2 dirs x 64 blocks)

__device__ __forceinline__ ushort f2bf(float f) {
  unsigned u = __builtin_bit_cast(unsigned, f);
  unsigned r = u + 0x7FFFu + ((u >> 16) & 1u);   // RNE
  return (ushort)(r >> 16);
}

__global__ __launch_bounds__(256) void k_xcvt(const float* __restrict__ x,
                                              ushort* __restrict__ xb, int n8) {
  int i = blockIdx.x * 256 + threadIdx.x;
  if (i >= n8) return;
  size_t off = (size_t)i * 8;
  float4 a = *reinterpret_cast<const float4*>(x + off);
  float4 b = *reinterpret_cast<const float4*>(x + off + 4);
  s8v o;
  o[0] = (short)f2bf(a.x); o[1] = (short)f2bf(a.y);
  o[2] = (short)f2bf(a.z); o[3] = (short)f2bf(a.w);
  o[4] = (short)f2bf(b.x); o[5] = (short)f2bf(b.y);
  o[6] = (short)f2bf(b.z); o[7] = (short)f2bf(b.w);
  *reinterpret_cast<s8v*>(xb + off) = o;
}

// Build permuted W^T (bf16): Wt[d][nb][p][k], p = gate*8+u, k<512 from Wih,
// k>=512 from Whh. One thread per (d, col); k-contiguous 16B stores.
__global__ __launch_bounds__(256) void k_wtprep(const float* __restrict__ WihF,
                                                const float* __restrict__ WhhF,
                                                const float* __restrict__ WihB,
                                                const float* __restrict__ WhhB,
                                                ushort* __restrict__ Wt) {
  int g = blockIdx.x * 256 + threadIdx.x;       // 0..4095
  int d = g >> 11, col = g & 2047;
  const float* Wih = d ? WihB : WihF;
  const float* Whh = d ? WhhB : WhhF;
  int gate = col >> 9, j = col & 511;
  int nb = j >> 3, u = j & 7, p = (gate << 3) | u;
  ushort* dst = Wt + (((size_t)(d * NB_DIR + nb) * COLS + p) << 10);
  for (int k0 = 0; k0 < KDIM; k0 += 8) {
    s8v o;
#pragma unroll
    for (int i = 0; i < 8; ++i) {
      int k = k0 + i;
      float v = (k < 512) ? Wih[k * 2048 + col] : Whh[(k - 512) * 2048 + col];
      o[i] = (short)f2bf(v);
    }
    *reinterpret_cast<s8v*>(dst + k0) = o;
  }
}

__global__ __launch_bounds__(256) void k_init(const float* __restrict__ bihF,
                                              const float* __restrict__ bhhF,
                                              const float* __restrict__ bihB,
                                              const float* __restrict__ bhhB,
                                              float* __restrict__ bias,
                                              unsigned* __restrict__ flg) {
  int g = blockIdx.x * 256 + threadIdx.x;
  if (g < 2048) {
    bias[g]        = bihF[g] + bhhF[g];
    bias[2048 + g] = bihB[g] + bhhB[g];
  }
  if (g < 128) flg[g] = 0u;
}

__global__ __launch_bounds__(256, 1) void k_lstm(const ushort* __restrict__ xb,
                                                 const ushort* __restrict__ Wt,
                                                 const float* __restrict__ bias,
                                                 float* __restrict__ out,
                                                 unsigned* flags) {
  __shared__ ushort Wlds[COLS][WP];             // 66 KB, full W slice
  __shared__ float gates[BATCH][COLS + 1];      // 8.4 KB
  __shared__ float cst[BATCH][HS];              // persistent c state
  __shared__ float biasl[COLS];

  const int tid  = threadIdx.x;
  const int dir  = blockIdx.x & 1;
  const int nb   = blockIdx.x >> 1;
  const int lane = tid & 63;
  const int w    = tid >> 6;                    // wave id == m-tile
  const int j0   = nb * HS;
  const int pc   = lane & 15;                   // frag col within n-tile
  const int kgrp = (lane >> 4) << 3;            // 0,8,16,24

  // stage full W slice (global -> LDS), once
  const ushort* wsrc = Wt + ((size_t)(dir * NB_DIR + nb) << 15);
  for (int v = tid; v < COLS * 128; v += 256) {
    int p = v >> 7, kk = (v & 127) << 3;
    *reinterpret_cast<s8v*>(&Wlds[p][kk]) =
        *reinterpret_cast<const s8v*>(wsrc + (p << 10) + kk);
  }
  if (tid < COLS)
    biasl[tid] = bias[dir * 2048 + ((tid >> 3) << 9) + j0 + (tid & 7)];
  for (int v = tid; v < BATCH * HS; v += 256) cst[v >> 3][v & 7] = 0.f;
  __syncthreads();

  const int arow = (w << 4) + (lane & 15);      // batch row for A frags

  float* outH  = out;                            // [512][64][1024]
  float* outHn = out + (size_t)33554432;
  float* outCn = outHn + 65536;
  unsigned* myflag   = flags + (dir << 6) + nb;
  unsigned* dirflags = flags + (dir << 6);

  // per-lane h read base: out[t-1][arow][dir*512 + kgrp]  (advances by 64K/step)
  const float* hsrc = out + ((size_t)arow << 10) + (dir << 9) + kgrp;

  // ---- prologue: x-part for t=0 (from LDS)
  f4v acc0 = {0.f, 0.f, 0.f, 0.f}, acc1 = {0.f, 0.f, 0.f, 0.f};
  {
    const ushort* xa = xb + ((size_t)arow << 9) + kgrp;
#pragma unroll
    for (int kb = 0; kb < 16; ++kb) {
      s8v a  = *reinterpret_cast<const s8v*>(xa + (kb << 5));
      s8v wb0 = *reinterpret_cast<const s8v*>(&Wlds[pc][(kb << 5) + kgrp]);
      s8v wb1 = *reinterpret_cast<const s8v*>(&Wlds[16 + pc][(kb << 5) + kgrp]);
      acc0 = __builtin_amdgcn_mfma_f32_16x16x32_bf16(a, wb0, acc0, 0, 0, 0);
      acc1 = __builtin_amdgcn_mfma_f32_16x16x32_bf16(a, wb1, acc1, 0, 0, 0);
    }
  }

  for (int t = 0; t < T_STEPS; ++t) {
    if (t > 0) {
      if (tid < 64) {                            // parallel flag poll (own dir)
        unsigned tgt = (unsigned)t;
        while (__hip_atomic_load(&dirflags[tid], __ATOMIC_RELAXED,
                                 __HIP_MEMORY_SCOPE_AGENT) < tgt)
          __builtin_amdgcn_s_sleep(1);           // throttle coherence traffic
      }
      __syncthreads();                           // orders h-loads after poll
      // ---- h-part GEMM: A-frags from out[t-1] (plain cached f32 loads,
      // cold lines fetch write-through data from L3; no reuse => no staleness)
      const float* ha = hsrc + (((size_t)t - 1) << 16);
#pragma unroll
      for (int kb = 0; kb < 16; ++kb) {
        const f4v* hp = reinterpret_cast<const f4v*>(ha + (kb << 5));
        f4v lo = hp[0], hi = hp[1];
        unsigned q0, q1, q2, q3;
        asm("v_cvt_pk_bf16_f32 %0, %1, %2" : "=v"(q0) : "v"(lo[0]), "v"(lo[1]));
        asm("v_cvt_pk_bf16_f32 %0, %1, %2" : "=v"(q1) : "v"(lo[2]), "v"(lo[3]));
        asm("v_cvt_pk_bf16_f32 %0, %1, %2" : "=v"(q2) : "v"(hi[0]), "v"(hi[1]));
        asm("v_cvt_pk_bf16_f32 %0, %1, %2" : "=v"(q3) : "v"(hi[2]), "v"(hi[3]));
        unsigned uv[4] = {q0, q1, q2, q3};
        s8v a = __builtin_bit_cast(s8v, uv);
        s8v wb0 = *reinterpret_cast<const s8v*>(&Wlds[pc][512 + (kb << 5) + kgrp]);
        s8v wb1 = *reinterpret_cast<const s8v*>(&Wlds[16 + pc][512 + (kb << 5) + kgrp]);
        acc0 = __builtin_amdgcn_mfma_f32_16x16x32_bf16(a, wb0, acc0, 0, 0, 0);
        acc1 = __builtin_amdgcn_mfma_f32_16x16x32_bf16(a, wb1, acc1, 0, 0, 0);
      }
    }
    // D layout: col = lane&15, row = (lane>>4)*4 + reg  [m89-verified]
    {
      int r0 = (w << 4) + ((lane >> 4) << 2);
#pragma unroll
      for (int r = 0; r < 4; ++r) {
        gates[r0 + r][pc]      = acc0[r];
        gates[r0 + r][16 + pc] = acc1[r];
      }
    }
    __syncthreads();
    // ---- elementwise: thread owns (b, 2 units); h published write-through
    {
      int b = tid >> 2, up = (tid & 3) << 1;
      float h2[2], c2[2];
#pragma unroll
      for (int e = 0; e < 2; ++e) {
        int u = up + e;
        float ig = gates[b][u]      + biasl[u];
        float fg = gates[b][8 + u]  + biasl[8 + u];
        float gg = gates[b][16 + u] + biasl[16 + u];
        float og = gates[b][24 + u] + biasl[24 + u];
        float cp = cst[b][u];
        float si = 1.f / (1.f + __expf(-ig));
        float sf = 1.f / (1.f + __expf(-fg));
        float so = 1.f / (1.f + __expf(-og));
        float tg = 1.f - 2.f / (__expf(2.f * gg) + 1.f);
        float c  = sf * cp + si * tg;
        float tc = 1.f - 2.f / (__expf(2.f * c) + 1.f);
        float h  = so * tc;
        cst[b][u] = c;
        h2[e] = h; c2[e] = c;
      }
      union { float f[2]; unsigned long long q; } hu;
      hu.f[0] = h2[0]; hu.f[1] = h2[1];
      size_t oc = ((size_t)b << 10) + (dir << 9) + j0 + up;
      unsigned long long* hb =
          reinterpret_cast<unsigned long long*>(outH + ((size_t)t << 16) + oc);
      __hip_atomic_store(hb, hu.q, __ATOMIC_RELAXED, __HIP_MEMORY_SCOPE_AGENT);
      if (t == T_STEPS - 1) {
        __builtin_nontemporal_store(h2[0], outHn + oc);
        __builtin_nontemporal_store(h2[1], outHn + oc + 1);
        __builtin_nontemporal_store(c2[0], outCn + oc);
        __builtin_nontemporal_store(c2[1], outCn + oc + 1);
      }
    }
    // barrier emits s_waitcnt vmcnt(0): write-through h stores are at the
    // coherence point before any thread proceeds => relaxed flag is safe.
    __syncthreads();
    if (tid == 0)
      __hip_atomic_store(myflag, (unsigned)(t + 1), __ATOMIC_RELAXED,
                         __HIP_MEMORY_SCOPE_AGENT);
    // ---- x-part for t+1 (from LDS), overlapped with other blocks' progress
    acc0 = (f4v){0.f, 0.f, 0.f, 0.f};
    acc1 = (f4v){0.f, 0.f, 0.f, 0.f};
    if (t < T_STEPS - 1) {
      const ushort* xa = xb + (((size_t)(t + 1) * BATCH + arow) << 9) + kgrp;
#pragma unroll
      for (int kb = 0; kb < 16; ++kb) {
        s8v a  = *reinterpret_cast<const s8v*>(xa + (kb << 5));
        s8v wb0 = *reinterpret_cast<const s8v*>(&Wlds[pc][(kb << 5) + kgrp]);
        s8v wb1 = *reinterpret_cast<const s8v*>(&Wlds[16 + pc][(kb << 5) + kgrp]);
        acc0 = __builtin_amdgcn_mfma_f32_16x16x32_bf16(a, wb0, acc0, 0, 0, 0);
        acc1 = __builtin_amdgcn_mfma_f32_16x16x32_bf16(a, wb1, acc1, 0, 0, 0);
      }
    }
  }
}

extern "C" void kernel_launch(void* const* d_in, const int* in_sizes, int n_in,
                              void* d_out, int out_size, void* d_ws, size_t ws_size,
                              hipStream_t stream) {
  const float* x    = (const float*)d_in[0];
  const float* WihF = (const float*)d_in[1];
  const float* WhhF = (const float*)d_in[2];
  const float* bihF = (const float*)d_in[3];
  const float* bhhF = (const float*)d_in[4];
  const float* WihB = (const float*)d_in[5];
  const float* WhhB = (const float*)d_in[6];
  const float* bihB = (const float*)d_in[7];
  const float* bhhB = (const float*)d_in[8];

  char* ws = (char*)d_ws;
  ushort*   xb   = (ushort*)(ws + WS_XB);
  ushort*   Wt   = (ushort*)(ws + WS_WT);
  float*    bias = (float*)(ws + WS_BIAS);
  unsigned* flg  = (unsigned*)(ws + WS_FLG);

  k_xcvt<<<8192, 256, 0, stream>>>(x, xb, 2097152);
  k_wtprep<<<16, 256, 0, stream>>>(WihF, WhhF, WihB, WhhB, Wt);
  k_init<<<8, 256, 0, stream>>>(bihF, bhhF, bihB, bhhB, bias, flg);
  k_lstm<<<NBLK, 256, 0, stream>>>(xb, Wt, bias, (float*)d_out, flg);
}